// Round 17
// baseline (489.964 us; speedup 1.0000x reference)
//
#include <hip/hip_runtime.h>
#include <hip/hip_bf16.h>

#define N_NODES  50000
#define N_EDGES  800000
#define E_TOT    850000   // edges + self loops
#define N_GRAPHS 64
#define NHID     64
#define NHEADS   4
#define HW       256      // NHEADS*NHID
#define NEG_SLOPE 0.2f
#define DEC_BLOCKS 512
#define ENC_NPB  32
#define SCAN_NB  ((N_NODES + 255) / 256)   // 196
#define MFMA_NPB 64                        // nodes per block in lin_mfma

typedef __attribute__((ext_vector_type(8))) short bf16x8;
typedef __attribute__((ext_vector_type(4))) float f32x4;

__device__ __forceinline__ float bf2f(unsigned short u) {
    return __uint_as_float(((unsigned)u) << 16);
}
__device__ __forceinline__ unsigned short f2bf(float f) {
    __hip_bfloat16 h = __float2bfloat16(f);
    return *reinterpret_cast<unsigned short*>(&h);
}
__device__ __forceinline__ float lrelu(float v) {
    return (v > 0.f) ? v : NEG_SLOPE * v;
}

// ---------------- encoder: Y = X = [x|pos] @ enc_w + enc_b (32 nodes/block, 2-node ILP) ----------------
__global__ __launch_bounds__(256) void encoder_kernel(
        const float* __restrict__ x, const float* __restrict__ pos,
        const float* __restrict__ enc_w, const float* __restrict__ enc_b,
        float* __restrict__ Y, float* __restrict__ X) {
    __shared__ float ws[128 * 64];       // 32 KB: whole enc_w
    __shared__ float xs[ENC_NPB][128];   // 16 KB: staged input rows
    int t = threadIdx.x;
    int base = blockIdx.x * ENC_NPB;
    int nx = min(ENC_NPB, N_NODES - base);
    for (int i = t; i < 128 * 64; i += 256) ws[i] = enc_w[i];
    for (int i = t; i < nx * 125; i += 256) {        // x rows are contiguous: coalesced
        int nn = i / 125, k = i - nn * 125;
        xs[nn][k] = x[(size_t)base * 125 + i];
    }
    for (int i = t; i < nx * 3; i += 256) {
        int nn = i / 3, k = i - nn * 3;
        xs[nn][125 + k] = pos[(size_t)(base + nn) * 3 + k];
    }
    __syncthreads();
    int c = t & 63, wv = t >> 6;
    float bias = enc_b[c];
    for (int nn = wv; nn < 16; nn += 4) {            // pair (nn, nn+16): 2 indep FMA chains
        int n2 = nn + 16;
        float acc0 = bias, acc1 = bias;
        #pragma unroll 16
        for (int k = 0; k < 128; ++k) {
            float w = ws[k * 64 + c];
            acc0 += xs[nn][k] * w;
            acc1 += xs[n2][k] * w;
        }
        if (nn < nx) { int n = base + nn; Y[n * 64 + c] = acc0; X[n * 64 + c] = acc0; }
        if (n2 < nx) { int n = base + n2; Y[n * 64 + c] = acc1; X[n * 64 + c] = acc1; }
    }
}

// ---------------- CSR build ----------------
__global__ void hist_kernel(const int* __restrict__ ei, int* __restrict__ counts) {
    int e = blockIdx.x * blockDim.x + threadIdx.x;
    if (e >= E_TOT) return;
    int d = (e < N_EDGES) ? ei[N_EDGES + e] : (e - N_EDGES);
    atomicAdd(&counts[d], 1);
}

__global__ __launch_bounds__(256) void scan_reduce_kernel(const int* __restrict__ counts,
                                                          int* __restrict__ bsum) {
    __shared__ int s[256];
    int t = threadIdx.x;
    int i = blockIdx.x * 256 + t;
    s[t] = (i < N_NODES) ? counts[i] : 0;
    __syncthreads();
    #pragma unroll
    for (int off = 128; off >= 1; off >>= 1) {
        if (t < off) s[t] += s[t + off];
        __syncthreads();
    }
    if (t == 0) bsum[blockIdx.x] = s[0];
}

__global__ __launch_bounds__(256) void scan_bsum_kernel(const int* __restrict__ bsum,
                                                        int* __restrict__ boff) {
    __shared__ int a[256];
    int t = threadIdx.x;
    int v = (t < SCAN_NB) ? bsum[t] : 0;
    a[t] = v;
    __syncthreads();
    #pragma unroll
    for (int off = 1; off < 256; off <<= 1) {
        int u = (t >= off) ? a[t - off] : 0;
        __syncthreads();
        a[t] += u;
        __syncthreads();
    }
    if (t < SCAN_NB) boff[t] = a[t] - v;   // exclusive
}

__global__ __launch_bounds__(256) void scan_write_kernel(const int* __restrict__ counts,
                                                         const int* __restrict__ boff,
                                                         int* __restrict__ row_ptr,
                                                         int* __restrict__ cursor) {
    __shared__ int a[256];
    int t = threadIdx.x;
    int i = blockIdx.x * 256 + t;
    int v = (i < N_NODES) ? counts[i] : 0;
    a[t] = v;
    __syncthreads();
    #pragma unroll
    for (int off = 1; off < 256; off <<= 1) {
        int u = (t >= off) ? a[t - off] : 0;
        __syncthreads();
        a[t] += u;
        __syncthreads();
    }
    if (i < N_NODES) {
        int ex = boff[blockIdx.x] + a[t] - v;
        row_ptr[i] = ex;
        cursor[i]  = ex;
        if (i == N_NODES - 1) row_ptr[N_NODES] = E_TOT;  // total is static
    }
}

__global__ void scatter_kernel(const int* __restrict__ ei, int* __restrict__ cursor,
                               int* __restrict__ col) {
    int e = blockIdx.x * blockDim.x + threadIdx.x;
    if (e >= E_TOT) return;
    int s, d;
    if (e < N_EDGES) { s = ei[e]; d = ei[N_EDGES + e]; }
    else             { s = d = e - N_EDGES; }
    int pos = atomicAdd(&cursor[d], 1);
    col[pos] = s;
}

// ---- Wt rows 512..519 = bf16(lin_w @ [att_src | att_dst]) per head; rows 520..527 zero ----
__global__ __launch_bounds__(256) void wa_precompute_kernel(
        const float* __restrict__ lin_w, const float* __restrict__ att_src,
        const float* __restrict__ att_dst, unsigned short* __restrict__ Wt) {
    int t = threadIdx.x;           // k = t>>2 (0..63), head = t&3
    int k = t >> 2, head = t & 3;
    float s = 0.f, d = 0.f;
    #pragma unroll 8
    for (int c = 0; c < 64; ++c) {
        float lw = lin_w[k * 256 + head * 64 + c];
        s += lw * att_src[head * 64 + c];
        d += lw * att_dst[head * 64 + c];
    }
    Wt[(size_t)(512 + head) * 64 + k] = f2bf(s);   // logit-src cols 0..3
    Wt[(size_t)(516 + head) * 64 + k] = f2bf(d);   // logit-dst cols 4..7
    Wt[(size_t)520 * 64 + t]       = 0;            // pad cols 8..15
    Wt[(size_t)520 * 64 + 256 + t] = 0;
}

// ---- Wt[n][k] = bf16 of (n<256 ? lin_w[k][n] : res_w[k][n-256]); 64 blocks x 256 thr ----
__global__ __launch_bounds__(256) void prep_wt_kernel(
        const float* __restrict__ lin_w, const float* __restrict__ res_w,
        unsigned short* __restrict__ Wt) {
    int k = blockIdx.x;        // 0..63
    int t = threadIdx.x;       // 0..255
    Wt[(size_t)t * 64 + k]         = f2bf(lin_w[k * 256 + t]);   // coalesced reads
    Wt[(size_t)(t + 256) * 64 + k] = f2bf(res_w[k * 256 + t]);
}

// ---- MFMA: [64 nodes x 64] @ [64 x 528] -> h (bf16) + res (bf16) + logits (fp32) ----
__global__ __launch_bounds__(256) void lin_mfma_kernel(
        const float* __restrict__ X, const unsigned short* __restrict__ Wt,
        __hip_bfloat16* __restrict__ h, __hip_bfloat16* __restrict__ res,
        float* __restrict__ a_src, float* __restrict__ a_dst) {
    __shared__ unsigned short As[64 * 64];    // 8 KB, XOR-swizzled rows
    __shared__ unsigned short Bs[256 * 64];   // 32 KB, XOR-swizzled rows
    int t = threadIdx.x;
    int lane = t & 63, w = t >> 6;
    int base = blockIdx.x * MFMA_NPB;
    bool full = (base + MFMA_NPB <= N_NODES);   // 781 of 782 blocks

    // ---- stage As: X fp32 -> bf16, row-swizzled ----
    for (int i = 0; i < 4; ++i) {
        int chunk = i * 256 + t;
        int row = chunk >> 4, q = chunk & 15;
        int node = base + row;
        float4 xv = make_float4(0.f, 0.f, 0.f, 0.f);
        if (full || node < N_NODES) xv = ((const float4*)X)[(size_t)node * 16 + q];
        ushort4 b;
        b.x = f2bf(xv.x); b.y = f2bf(xv.y); b.z = f2bf(xv.z); b.w = f2bf(xv.w);
        int idx = row * 64 + ((q * 4) ^ ((row & 7) << 3));
        *(ushort4*)&As[idx] = b;
    }

    int rowl = (w << 4) + (lane & 15);
    int kg   = (lane >> 4) << 3;
    int amask = (lane & 7) << 3;
    bf16x8 af0, af1;

    for (int p = 0; p < 2; ++p) {
        __syncthreads();     // p0: As ready; p1: all waves done with p0 tiles + af loads
        const unsigned short* Wp = Wt + (size_t)p * 256 * 64;
        for (int i = 0; i < 8; ++i) {
            int chunk = i * 256 + t;
            int n = chunk >> 3, c = chunk & 7;
            int idx = n * 64 + ((c * 8) ^ ((n & 7) << 3));
            *(uint4*)&Bs[idx] = *(const uint4*)(Wp + chunk * 8);
        }
        if (p == 1 && t < 128) {
            // stage logit-weight tile (Wt rows 512..527) into the now-dead As region
            int n = t >> 3, c = t & 7;
            int idx = n * 64 + ((c * 8) ^ ((n & 7) << 3));
            *(uint4*)&As[idx] = *(const uint4*)(Wt + (size_t)(512 + n) * 64 + c * 8);
        }
        __syncthreads();
        if (p == 0) {        // a-frags valid for both phases; As dead afterwards
            af0 = *(bf16x8*)&As[rowl * 64 + (kg ^ amask)];
            af1 = *(bf16x8*)&As[rowl * 64 + ((32 + kg) ^ amask)];
        }
        int rowbase = base + (w << 4) + ((lane >> 4) << 2);
        for (int ct = 0; ct < 16; ++ct) {
            int coll = (ct << 4) + (lane & 15);
            bf16x8 bf0 = *(bf16x8*)&Bs[coll * 64 + (kg ^ amask)];
            bf16x8 bf1 = *(bf16x8*)&Bs[coll * 64 + ((32 + kg) ^ amask)];
            f32x4 acc = {0.f, 0.f, 0.f, 0.f};
            acc = __builtin_amdgcn_mfma_f32_16x16x32_bf16(af0, bf0, acc, 0, 0, 0);
            acc = __builtin_amdgcn_mfma_f32_16x16x32_bf16(af1, bf1, acc, 0, 0, 0);
            if (full) {
                __hip_bfloat16* dst = (p == 0) ? h : res;
                #pragma unroll
                for (int r = 0; r < 4; ++r)
                    dst[(size_t)(rowbase + r) * 256 + coll] = __float2bfloat16(acc[r]);
            } else {
                #pragma unroll
                for (int r = 0; r < 4; ++r) {
                    int rn = rowbase + r;
                    if (rn < N_NODES) {
                        if (p == 0) h[(size_t)rn * 256 + coll] = __float2bfloat16(acc[r]);
                        else        res[(size_t)rn * 256 + coll] = __float2bfloat16(acc[r]);
                    }
                }
            }
        }
        if (p == 1) {
            // ---- logit tile: cols 0..3 = a_src heads, 4..7 = a_dst heads ----
            int coll = lane & 15;
            bf16x8 bf0 = *(bf16x8*)&As[coll * 64 + (kg ^ amask)];
            bf16x8 bf1 = *(bf16x8*)&As[coll * 64 + ((32 + kg) ^ amask)];
            f32x4 acc = {0.f, 0.f, 0.f, 0.f};
            acc = __builtin_amdgcn_mfma_f32_16x16x32_bf16(af0, bf0, acc, 0, 0, 0);
            acc = __builtin_amdgcn_mfma_f32_16x16x32_bf16(af1, bf1, acc, 0, 0, 0);
            #pragma unroll
            for (int r = 0; r < 4; ++r) {
                int rn = rowbase + r;
                if (rn < N_NODES) {
                    if (coll < 4)      a_src[rn * 4 + coll] = acc[r];
                    else if (coll < 8) a_dst[rn * 4 + (coll - 4)] = acc[r];
                }
            }
        }
    }
}

// ---- FUSED: softmax (raw-e table, deferred 1/z) + gather x8 + bf16 res + elu + mix + update ----
__global__ __launch_bounds__(256) void fused_gat_kernel(
        const int* __restrict__ rp, const int* __restrict__ col,
        const float* __restrict__ a_src, const float* __restrict__ a_dst,
        const __hip_bfloat16* __restrict__ h,
        const float* __restrict__ conv_b,
        const __hip_bfloat16* __restrict__ res,
        float* __restrict__ Y, float* __restrict__ X) {
    __shared__ float satt[4][64][4];   // per-wave RAW exp weights (unnormalized)
    __shared__ int   scol[4][64];      // per-wave src byte-offsets (s*512)
    int n = (blockIdx.x * blockDim.x + threadIdx.x) >> 6;
    if (n >= N_NODES) return;
    int lane = threadIdx.x & 63;
    int w = (threadIdx.x >> 6) & 3;
    int head = lane >> 4;
    int base = rp[n];
    int deg  = rp[n + 1] - base;
    const char* hb = (const char*)h;
    size_t loff = (size_t)lane * 8;
    float4 ad = ((const float4*)a_dst)[n];

    float a0 = 0.f, a1 = 0.f, a2 = 0.f, a3 = 0.f;
    float invz;

    if (deg <= 64) {
        int s = 0;
        float l0 = -3.0e38f, l1 = -3.0e38f, l2 = -3.0e38f, l3 = -3.0e38f;
        if (lane < deg) {
            s = col[base + lane];                       // coalesced
            float4 as = ((const float4*)a_src)[s];      // one 16B gather per edge
            l0 = lrelu(as.x + ad.x); l1 = lrelu(as.y + ad.y);
            l2 = lrelu(as.z + ad.z); l3 = lrelu(as.w + ad.w);
        }
        float m0 = l0, m1 = l1, m2 = l2, m3 = l3;
        #pragma unroll
        for (int off = 1; off < 64; off <<= 1) {
            m0 = fmaxf(m0, __shfl_xor(m0, off)); m1 = fmaxf(m1, __shfl_xor(m1, off));
            m2 = fmaxf(m2, __shfl_xor(m2, off)); m3 = fmaxf(m3, __shfl_xor(m3, off));
        }
        float e0 = (lane < deg) ? __expf(l0 - m0) : 0.f;
        float e1 = (lane < deg) ? __expf(l1 - m1) : 0.f;
        float e2 = (lane < deg) ? __expf(l2 - m2) : 0.f;
        float e3 = (lane < deg) ? __expf(l3 - m3) : 0.f;
        float z0 = e0, z1 = e1, z2 = e2, z3 = e3;
        #pragma unroll
        for (int off = 1; off < 64; off <<= 1) {
            z0 += __shfl_xor(z0, off); z1 += __shfl_xor(z1, off);
            z2 += __shfl_xor(z2, off); z3 += __shfl_xor(z3, off);
        }
        // raw-e table (wave-synchronous); normalization deferred to epilogue
        satt[w][lane][0] = e0; satt[w][lane][1] = e1;
        satt[w][lane][2] = e2; satt[w][lane][3] = e3;
        scol[w][lane] = s << 9;          // byte offset: s * 256 ushorts * 2B
        float zh = (head == 0) ? z0 : (head == 1) ? z1 : (head == 2) ? z2 : z3;
        invz = 1.0f / zh;

        int j = 0;
        for (; j + 8 <= deg; j += 8) {       // 8 gathers in flight
            int   s0 = scol[w][j],       s1 = scol[w][j + 1];
            int   s2 = scol[w][j + 2],   s3 = scol[w][j + 3];
            int   s4 = scol[w][j + 4],   s5 = scol[w][j + 5];
            int   s6 = scol[w][j + 6],   s7 = scol[w][j + 7];
            float w0 = satt[w][j][head],     w1 = satt[w][j + 1][head];
            float w2 = satt[w][j + 2][head], w3 = satt[w][j + 3][head];
            float w4 = satt[w][j + 4][head], w5 = satt[w][j + 5][head];
            float w6 = satt[w][j + 6][head], w7 = satt[w][j + 7][head];
            ushort4 v0 = *(const ushort4*)(hb + s0 + loff);
            ushort4 v1 = *(const ushort4*)(hb + s1 + loff);
            ushort4 v2 = *(const ushort4*)(hb + s2 + loff);
            ushort4 v3 = *(const ushort4*)(hb + s3 + loff);
            ushort4 v4 = *(const ushort4*)(hb + s4 + loff);
            ushort4 v5 = *(const ushort4*)(hb + s5 + loff);
            ushort4 v6 = *(const ushort4*)(hb + s6 + loff);
            ushort4 v7 = *(const ushort4*)(hb + s7 + loff);
            a0 += w0 * bf2f(v0.x) + w1 * bf2f(v1.x) + w2 * bf2f(v2.x) + w3 * bf2f(v3.x)
                + w4 * bf2f(v4.x) + w5 * bf2f(v5.x) + w6 * bf2f(v6.x) + w7 * bf2f(v7.x);
            a1 += w0 * bf2f(v0.y) + w1 * bf2f(v1.y) + w2 * bf2f(v2.y) + w3 * bf2f(v3.y)
                + w4 * bf2f(v4.y) + w5 * bf2f(v5.y) + w6 * bf2f(v6.y) + w7 * bf2f(v7.y);
            a2 += w0 * bf2f(v0.z) + w1 * bf2f(v1.z) + w2 * bf2f(v2.z) + w3 * bf2f(v3.z)
                + w4 * bf2f(v4.z) + w5 * bf2f(v5.z) + w6 * bf2f(v6.z) + w7 * bf2f(v7.z);
            a3 += w0 * bf2f(v0.w) + w1 * bf2f(v1.w) + w2 * bf2f(v2.w) + w3 * bf2f(v3.w)
                + w4 * bf2f(v4.w) + w5 * bf2f(v5.w) + w6 * bf2f(v6.w) + w7 * bf2f(v7.w);
        }
        for (; j + 4 <= deg; j += 4) {
            int   s0 = scol[w][j],       s1 = scol[w][j + 1];
            int   s2 = scol[w][j + 2],   s3 = scol[w][j + 3];
            float w0 = satt[w][j][head],     w1 = satt[w][j + 1][head];
            float w2 = satt[w][j + 2][head], w3 = satt[w][j + 3][head];
            ushort4 v0 = *(const ushort4*)(hb + s0 + loff);
            ushort4 v1 = *(const ushort4*)(hb + s1 + loff);
            ushort4 v2 = *(const ushort4*)(hb + s2 + loff);
            ushort4 v3 = *(const ushort4*)(hb + s3 + loff);
            a0 += w0 * bf2f(v0.x) + w1 * bf2f(v1.x) + w2 * bf2f(v2.x) + w3 * bf2f(v3.x);
            a1 += w0 * bf2f(v0.y) + w1 * bf2f(v1.y) + w2 * bf2f(v2.y) + w3 * bf2f(v3.y);
            a2 += w0 * bf2f(v0.z) + w1 * bf2f(v1.z) + w2 * bf2f(v2.z) + w3 * bf2f(v3.z);
            a3 += w0 * bf2f(v0.w) + w1 * bf2f(v1.w) + w2 * bf2f(v2.w) + w3 * bf2f(v3.w);
        }
        for (; j < deg; ++j) {
            int   s0 = scol[w][j];
            float w0 = satt[w][j][head];
            ushort4 v0 = *(const ushort4*)(hb + s0 + loff);
            a0 += w0 * bf2f(v0.x); a1 += w0 * bf2f(v0.y);
            a2 += w0 * bf2f(v0.z); a3 += w0 * bf2f(v0.w);
        }
    } else {
        // ---- rare fallback (deg > 64): chunked online softmax, then weighted gather ----
        float m0 = -3.0e38f, m1 = -3.0e38f, m2 = -3.0e38f, m3 = -3.0e38f;
        float z0 = 0.f, z1 = 0.f, z2 = 0.f, z3 = 0.f;
        for (int c0 = 0; c0 < deg; c0 += 64) {
            int j = c0 + lane;
            float l0 = -3.0e38f, l1 = -3.0e38f, l2 = -3.0e38f, l3 = -3.0e38f;
            if (j < deg) {
                int s = col[base + j];
                float4 as = ((const float4*)a_src)[s];
                l0 = lrelu(as.x + ad.x); l1 = lrelu(as.y + ad.y);
                l2 = lrelu(as.z + ad.z); l3 = lrelu(as.w + ad.w);
            }
            float c0m = l0, c1m = l1, c2m = l2, c3m = l3;
            #pragma unroll
            for (int off = 1; off < 64; off <<= 1) {
                c0m = fmaxf(c0m, __shfl_xor(c0m, off)); c1m = fmaxf(c1m, __shfl_xor(c1m, off));
                c2m = fmaxf(c2m, __shfl_xor(c2m, off)); c3m = fmaxf(c3m, __shfl_xor(c3m, off));
            }
            float n0 = fmaxf(m0, c0m), n1 = fmaxf(m1, c1m);
            float n2 = fmaxf(m2, c2m), n3 = fmaxf(m3, c3m);
            z0 *= __expf(m0 - n0); z1 *= __expf(m1 - n1);
            z2 *= __expf(m2 - n2); z3 *= __expf(m3 - n3);
            m0 = n0; m1 = n1; m2 = n2; m3 = n3;
            float e0 = (j < deg) ? __expf(l0 - m0) : 0.f;
            float e1 = (j < deg) ? __expf(l1 - m1) : 0.f;
            float e2 = (j < deg) ? __expf(l2 - m2) : 0.f;
            float e3 = (j < deg) ? __expf(l3 - m3) : 0.f;
            #pragma unroll
            for (int off = 1; off < 64; off <<= 1) {
                e0 += __shfl_xor(e0, off); e1 += __shfl_xor(e1, off);
                e2 += __shfl_xor(e2, off); e3 += __shfl_xor(e3, off);
            }
            z0 += e0; z1 += e1; z2 += e2; z3 += e3;
        }
        float zh = (head == 0) ? z0 : (head == 1) ? z1 : (head == 2) ? z2 : z3;
        invz = 1.0f / zh;
        for (int c0 = 0; c0 < deg; c0 += 64) {
            int j = c0 + lane;
            int s = 0;
            float e0 = 0.f, e1 = 0.f, e2 = 0.f, e3 = 0.f;
            if (j < deg) {
                s = col[base + j];
                float4 as = ((const float4*)a_src)[s];
                e0 = __expf(lrelu(as.x + ad.x) - m0);
                e1 = __expf(lrelu(as.y + ad.y) - m1);
                e2 = __expf(lrelu(as.z + ad.z) - m2);
                e3 = __expf(lrelu(as.w + ad.w) - m3);
            }
            satt[w][lane][0] = e0; satt[w][lane][1] = e1;
            satt[w][lane][2] = e2; satt[w][lane][3] = e3;
            scol[w][lane] = s << 9;
            int cnt = min(64, deg - c0);
            for (int jj = 0; jj < cnt; ++jj) {
                int   sj = scol[w][jj];
                float ww = satt[w][jj][head];
                ushort4 v = *(const ushort4*)(hb + sj + loff);
                a0 += ww * bf2f(v.x); a1 += ww * bf2f(v.y);
                a2 += ww * bf2f(v.z); a3 += ww * bf2f(v.w);
            }
        }
    }

    // ---- deferred normalization, bf16 residual, elu, lane-local head-mix, update ----
    a0 *= invz; a1 *= invz; a2 *= invz; a3 *= invz;
    ushort4 rr4 = ((const ushort4*)res)[(size_t)n * 64 + lane];   // 8B/lane coalesced
    float4 cb = ((const float4*)conv_b)[lane];
    float v0 = a0 + cb.x + bf2f(rr4.x), v1 = a1 + cb.y + bf2f(rr4.y);
    float v2 = a2 + cb.z + bf2f(rr4.z), v3 = a3 + cb.w + bf2f(rr4.w);
    v0 = (v0 > 0.f) ? v0 : (__expf(v0) - 1.f);
    v1 = (v1 > 0.f) ? v1 : (__expf(v1) - 1.f);
    v2 = (v2 > 0.f) ? v2 : (__expf(v2) - 1.f);
    v3 = (v3 > 0.f) ? v3 : (__expf(v3) - 1.f);
    float mixed = 0.25f * (v0 + v1 + v2 + v3);

    float xv = X[n * 64 + lane];
    float y = Y[n * 64 + lane];
    y  = y + (mixed - y - xv);    // DT=ALPHA=GAMMA=1
    xv = xv + y;
    Y[n * 64 + lane] = y;
    X[n * 64 + lane] = xv;
}

// ---------------- decoder: per-block partials (no global atomics) ----------------
__global__ void decoder_partial_kernel(const float* __restrict__ X, const float* __restrict__ dec_w,
                                       const float* __restrict__ dec_b, const int* __restrict__ batch,
                                       float* __restrict__ partials) {
    __shared__ float sg[N_GRAPHS];
    int t = threadIdx.x;                      // 256 threads = 4 waves
    if (t < N_GRAPHS) sg[t] = 0.f;
    __syncthreads();
    int lane = t & 63;
    int wave = t >> 6;
    const int npb = (N_NODES + DEC_BLOCKS - 1) / DEC_BLOCKS;   // 98
    int start = blockIdx.x * npb;
    int end   = min(start + npb, N_NODES);
    float dw = dec_w[lane];
    float db = dec_b[0];
    for (int n = start + wave; n < end; n += 4) {
        float p = X[n * 64 + lane] * dw;
        #pragma unroll
        for (int off = 32; off >= 1; off >>= 1) p += __shfl_down(p, off);
        if (lane == 0) atomicAdd(&sg[batch[n]], p + db);
    }
    __syncthreads();
    if (t < N_GRAPHS) partials[blockIdx.x * N_GRAPHS + t] = sg[t];
}

__global__ void decoder_reduce_kernel(const float* __restrict__ partials, float* __restrict__ out) {
    __shared__ float red[256];
    int t = threadIdx.x;
    int g = t & 63, j = t >> 6;
    float s = 0.f;
    for (int b = j * (DEC_BLOCKS / 4); b < (j + 1) * (DEC_BLOCKS / 4); ++b)
        s += partials[b * N_GRAPHS + g];
    red[t] = s;
    __syncthreads();
    if (t < 64) out[g] = red[g] + red[64 + g] + red[128 + g] + red[192 + g];
}

extern "C" void kernel_launch(void* const* d_in, const int* in_sizes, int n_in,
                              void* d_out, int out_size, void* d_ws, size_t ws_size,
                              hipStream_t stream) {
    const float* x       = (const float*)d_in[0];
    const float* pos     = (const float*)d_in[1];
    const int*   ei      = (const int*)d_in[2];
    const int*   batch   = (const int*)d_in[3];
    const float* enc_w   = (const float*)d_in[4];
    const float* enc_b   = (const float*)d_in[5];
    const float* res_w   = (const float*)d_in[6];
    const float* res_b   = (const float*)d_in[7];
    const float* lin_w   = (const float*)d_in[8];
    const float* att_src = (const float*)d_in[9];
    const float* att_dst = (const float*)d_in[10];
    const float* conv_b  = (const float*)d_in[11];
    const float* dec_w   = (const float*)d_in[12];
    const float* dec_b   = (const float*)d_in[13];
    float* out = (float*)d_out;

    char* ws = (char*)d_ws;
    size_t off = 0;
    auto alloc = [&](size_t bytes) -> void* {
        void* p = ws + off;
        off += (bytes + 255) & ~size_t(255);
        return p;
    };
    float* Y       = (float*)alloc((size_t)N_NODES * 64 * sizeof(float));
    float* X       = (float*)alloc((size_t)N_NODES * 64 * sizeof(float));
    __hip_bfloat16* h   = (__hip_bfloat16*)alloc((size_t)N_NODES * HW * sizeof(__hip_bfloat16));
    __hip_bfloat16* res = (__hip_bfloat16*)alloc((size_t)N_NODES * HW * sizeof(__hip_bfloat16));
    float* a_src   = (float*)alloc((size_t)N_NODES * NHEADS * sizeof(float));
    float* a_dst   = (float*)alloc((size_t)N_NODES * NHEADS * sizeof(float));
    unsigned short* Wt = (unsigned short*)alloc((size_t)528 * 64 * sizeof(unsigned short));
    float* partials= (float*)alloc((size_t)DEC_BLOCKS * N_GRAPHS * sizeof(float));
    int*   counts  = (int*)alloc((size_t)N_NODES * sizeof(int));
    int*   row_ptr = (int*)alloc((size_t)(N_NODES + 1) * sizeof(int));
    int*   cursor  = (int*)alloc((size_t)N_NODES * sizeof(int));
    int*   col     = (int*)alloc((size_t)E_TOT * sizeof(int));
    int*   bsum    = (int*)alloc((size_t)SCAN_NB * sizeof(int));
    int*   boff    = (int*)alloc((size_t)SCAN_NB * sizeof(int));

    // ---- CSR build (dst is static; built each call for determinism) ----
    hipMemsetAsync(counts, 0, (size_t)N_NODES * sizeof(int), stream);
    const int eb = (E_TOT + 255) / 256;
    hist_kernel<<<eb, 256, 0, stream>>>(ei, counts);
    scan_reduce_kernel<<<SCAN_NB, 256, 0, stream>>>(counts, bsum);
    scan_bsum_kernel<<<1, 256, 0, stream>>>(bsum, boff);
    scan_write_kernel<<<SCAN_NB, 256, 0, stream>>>(counts, boff, row_ptr, cursor);
    scatter_kernel<<<eb, 256, 0, stream>>>(ei, cursor, col);

    wa_precompute_kernel<<<1, 256, 0, stream>>>(lin_w, att_src, att_dst, Wt);
    prep_wt_kernel<<<64, 256, 0, stream>>>(lin_w, res_w, Wt);
    encoder_kernel<<<(N_NODES + ENC_NPB - 1) / ENC_NPB, 256, 0, stream>>>(
        x, pos, enc_w, enc_b, Y, X);

    const int ab = (N_NODES * 64 + 255) / 256;   // one wave per node
    const int mb = (N_NODES + MFMA_NPB - 1) / MFMA_NPB;   // 782
    for (int layer = 0; layer < 3; ++layer) {
        lin_mfma_kernel<<<mb, 256, 0, stream>>>(X, Wt, h, res, a_src, a_dst);
        fused_gat_kernel<<<ab, 256, 0, stream>>>(row_ptr, col, a_src, a_dst, h,
                                                 conv_b, res, Y, X);
    }

    decoder_partial_kernel<<<DEC_BLOCKS, 256, 0, stream>>>(X, dec_w, dec_b, batch, partials);
    decoder_reduce_kernel<<<1, 256, 0, stream>>>(partials, out);
}

// Round 18
// 478.312 us; speedup vs baseline: 1.0244x; 1.0244x over previous
//
#include <hip/hip_runtime.h>
#include <hip/hip_bf16.h>

#define N_NODES  50000
#define N_EDGES  800000
#define E_TOT    850000   // edges + self loops
#define N_GRAPHS 64
#define NHID     64
#define NHEADS   4
#define HW       256      // NHEADS*NHID
#define NEG_SLOPE 0.2f
#define DEC_BLOCKS 512
#define ENC_NPB  32
#define SCAN_NB  ((N_NODES + 255) / 256)   // 196
#define MFMA_NPB 128                       // nodes per block in lin_mfma

typedef __attribute__((ext_vector_type(8))) short bf16x8;
typedef __attribute__((ext_vector_type(4))) float f32x4;

__device__ __forceinline__ float bf2f(unsigned short u) {
    return __uint_as_float(((unsigned)u) << 16);
}
__device__ __forceinline__ unsigned short f2bf(float f) {
    __hip_bfloat16 h = __float2bfloat16(f);
    return *reinterpret_cast<unsigned short*>(&h);
}
__device__ __forceinline__ float lrelu(float v) {
    return (v > 0.f) ? v : NEG_SLOPE * v;
}

// ---------------- encoder: Y = X = [x|pos] @ enc_w + enc_b (32 nodes/block, 2-node ILP) ----------------
__global__ __launch_bounds__(256) void encoder_kernel(
        const float* __restrict__ x, const float* __restrict__ pos,
        const float* __restrict__ enc_w, const float* __restrict__ enc_b,
        float* __restrict__ Y, float* __restrict__ X) {
    __shared__ float ws[128 * 64];       // 32 KB: whole enc_w
    __shared__ float xs[ENC_NPB][128];   // 16 KB: staged input rows
    int t = threadIdx.x;
    int base = blockIdx.x * ENC_NPB;
    int nx = min(ENC_NPB, N_NODES - base);
    for (int i = t; i < 128 * 64; i += 256) ws[i] = enc_w[i];
    for (int i = t; i < nx * 125; i += 256) {        // x rows are contiguous: coalesced
        int nn = i / 125, k = i - nn * 125;
        xs[nn][k] = x[(size_t)base * 125 + i];
    }
    for (int i = t; i < nx * 3; i += 256) {
        int nn = i / 3, k = i - nn * 3;
        xs[nn][125 + k] = pos[(size_t)(base + nn) * 3 + k];
    }
    __syncthreads();
    int c = t & 63, wv = t >> 6;
    float bias = enc_b[c];
    for (int nn = wv; nn < 16; nn += 4) {            // pair (nn, nn+16): 2 indep FMA chains
        int n2 = nn + 16;
        float acc0 = bias, acc1 = bias;
        #pragma unroll 16
        for (int k = 0; k < 128; ++k) {
            float w = ws[k * 64 + c];
            acc0 += xs[nn][k] * w;
            acc1 += xs[n2][k] * w;
        }
        if (nn < nx) { int n = base + nn; Y[n * 64 + c] = acc0; X[n * 64 + c] = acc0; }
        if (n2 < nx) { int n = base + n2; Y[n * 64 + c] = acc1; X[n * 64 + c] = acc1; }
    }
}

// ---------------- CSR build ----------------
__global__ void hist_kernel(const int* __restrict__ ei, int* __restrict__ counts) {
    int e = blockIdx.x * blockDim.x + threadIdx.x;
    if (e >= E_TOT) return;
    int d = (e < N_EDGES) ? ei[N_EDGES + e] : (e - N_EDGES);
    atomicAdd(&counts[d], 1);
}

__global__ __launch_bounds__(256) void scan_reduce_kernel(const int* __restrict__ counts,
                                                          int* __restrict__ bsum) {
    __shared__ int s[256];
    int t = threadIdx.x;
    int i = blockIdx.x * 256 + t;
    s[t] = (i < N_NODES) ? counts[i] : 0;
    __syncthreads();
    #pragma unroll
    for (int off = 128; off >= 1; off >>= 1) {
        if (t < off) s[t] += s[t + off];
        __syncthreads();
    }
    if (t == 0) bsum[blockIdx.x] = s[0];
}

__global__ __launch_bounds__(256) void scan_bsum_kernel(const int* __restrict__ bsum,
                                                        int* __restrict__ boff) {
    __shared__ int a[256];
    int t = threadIdx.x;
    int v = (t < SCAN_NB) ? bsum[t] : 0;
    a[t] = v;
    __syncthreads();
    #pragma unroll
    for (int off = 1; off < 256; off <<= 1) {
        int u = (t >= off) ? a[t - off] : 0;
        __syncthreads();
        a[t] += u;
        __syncthreads();
    }
    if (t < SCAN_NB) boff[t] = a[t] - v;   // exclusive
}

__global__ __launch_bounds__(256) void scan_write_kernel(const int* __restrict__ counts,
                                                         const int* __restrict__ boff,
                                                         int* __restrict__ row_ptr,
                                                         int* __restrict__ cursor) {
    __shared__ int a[256];
    int t = threadIdx.x;
    int i = blockIdx.x * 256 + t;
    int v = (i < N_NODES) ? counts[i] : 0;
    a[t] = v;
    __syncthreads();
    #pragma unroll
    for (int off = 1; off < 256; off <<= 1) {
        int u = (t >= off) ? a[t - off] : 0;
        __syncthreads();
        a[t] += u;
        __syncthreads();
    }
    if (i < N_NODES) {
        int ex = boff[blockIdx.x] + a[t] - v;
        row_ptr[i] = ex;
        cursor[i]  = ex;
        if (i == N_NODES - 1) row_ptr[N_NODES] = E_TOT;  // total is static
    }
}

__global__ void scatter_kernel(const int* __restrict__ ei, int* __restrict__ cursor,
                               int* __restrict__ col) {
    int e = blockIdx.x * blockDim.x + threadIdx.x;
    if (e >= E_TOT) return;
    int s, d;
    if (e < N_EDGES) { s = ei[e]; d = ei[N_EDGES + e]; }
    else             { s = d = e - N_EDGES; }
    int pos = atomicAdd(&cursor[d], 1);
    col[pos] = s;
}

// ---- Wt[n][k] = bf16 of (n<256 ? lin_w : res_w); rows 512..519 = logit weights; 520..527 pad ----
__global__ __launch_bounds__(256) void prep_wt_kernel(
        const float* __restrict__ lin_w, const float* __restrict__ res_w,
        const float* __restrict__ att_src, const float* __restrict__ att_dst,
        unsigned short* __restrict__ Wt) {
    int k = blockIdx.x;        // 0..63
    int t = threadIdx.x;       // 0..255
    Wt[(size_t)t * 64 + k]         = f2bf(lin_w[k * 256 + t]);   // coalesced reads
    Wt[(size_t)(t + 256) * 64 + k] = f2bf(res_w[k * 256 + t]);
    if (blockIdx.x == 0) {     // fold wa-precompute into block 0
        int kk = t >> 2, head = t & 3;
        float s = 0.f, d = 0.f;
        #pragma unroll 8
        for (int c = 0; c < 64; ++c) {
            float lw = lin_w[kk * 256 + head * 64 + c];
            s += lw * att_src[head * 64 + c];
            d += lw * att_dst[head * 64 + c];
        }
        Wt[(size_t)(512 + head) * 64 + kk] = f2bf(s);   // logit-src cols 0..3
        Wt[(size_t)(516 + head) * 64 + kk] = f2bf(d);   // logit-dst cols 4..7
        Wt[(size_t)520 * 64 + t]       = 0;             // pad cols 8..15
        Wt[(size_t)520 * 64 + 256 + t] = 0;
    }
}

// ---- MFMA: [128 nodes x 64] @ [64 x 528] -> h (bf16) + res (bf16) + logits (fp32) ----
// wave w owns row-tiles w and w+4; Bs staging amortized over 128 nodes
__global__ __launch_bounds__(256) void lin_mfma_kernel(
        const float* __restrict__ X, const unsigned short* __restrict__ Wt,
        __hip_bfloat16* __restrict__ h, __hip_bfloat16* __restrict__ res,
        float* __restrict__ a_src, float* __restrict__ a_dst) {
    __shared__ unsigned short As[128 * 64];   // 16 KB, XOR-swizzled rows
    __shared__ unsigned short Bs[256 * 64];   // 32 KB, XOR-swizzled rows
    int t = threadIdx.x;
    int lane = t & 63, w = t >> 6;
    int base = blockIdx.x * MFMA_NPB;
    bool full = (base + MFMA_NPB <= N_NODES);   // 390 of 391 blocks

    // ---- stage As: X fp32 -> bf16, row-swizzled; 2048 f4-chunks / 256 thr ----
    for (int i = 0; i < 8; ++i) {
        int chunk = i * 256 + t;
        int row = chunk >> 4, q = chunk & 15;
        int node = base + row;
        float4 xv = make_float4(0.f, 0.f, 0.f, 0.f);
        if (full || node < N_NODES) xv = ((const float4*)X)[(size_t)node * 16 + q];
        ushort4 b;
        b.x = f2bf(xv.x); b.y = f2bf(xv.y); b.z = f2bf(xv.z); b.w = f2bf(xv.w);
        int idx = row * 64 + ((q * 4) ^ ((row & 7) << 3));
        *(ushort4*)&As[idx] = b;
    }

    int kg   = (lane >> 4) << 3;
    int amask = (lane & 7) << 3;
    bf16x8 afA0, afA1, afB0, afB1;

    for (int p = 0; p < 2; ++p) {
        __syncthreads();     // p0: As ready; p1: all waves done with p0 tiles + af loads
        const unsigned short* Wp = Wt + (size_t)p * 256 * 64;
        for (int i = 0; i < 8; ++i) {
            int chunk = i * 256 + t;
            int n = chunk >> 3, c = chunk & 7;
            int idx = n * 64 + ((c * 8) ^ ((n & 7) << 3));
            *(uint4*)&Bs[idx] = *(const uint4*)(Wp + chunk * 8);
        }
        if (p == 1 && t < 128) {
            // stage logit-weight tile (Wt rows 512..527) into the now-dead As region
            int n = t >> 3, c = t & 7;
            int idx = n * 64 + ((c * 8) ^ ((n & 7) << 3));
            *(uint4*)&As[idx] = *(const uint4*)(Wt + (size_t)(512 + n) * 64 + c * 8);
        }
        __syncthreads();
        if (p == 0) {        // a-frags for both row-tiles; As dead afterwards
            int rowlA = (w << 4) + (lane & 15);
            int rowlB = rowlA + 64;
            afA0 = *(bf16x8*)&As[rowlA * 64 + (kg ^ amask)];
            afA1 = *(bf16x8*)&As[rowlA * 64 + ((32 + kg) ^ amask)];
            afB0 = *(bf16x8*)&As[rowlB * 64 + (kg ^ amask)];
            afB1 = *(bf16x8*)&As[rowlB * 64 + ((32 + kg) ^ amask)];
        }
        int rowbaseA = base + (w << 4) + ((lane >> 4) << 2);
        int rowbaseB = rowbaseA + 64;
        for (int ct = 0; ct < 16; ++ct) {
            int coll = (ct << 4) + (lane & 15);
            bf16x8 bf0 = *(bf16x8*)&Bs[coll * 64 + (kg ^ amask)];
            bf16x8 bf1 = *(bf16x8*)&Bs[coll * 64 + ((32 + kg) ^ amask)];
            f32x4 accA = {0.f, 0.f, 0.f, 0.f};
            f32x4 accB = {0.f, 0.f, 0.f, 0.f};
            accA = __builtin_amdgcn_mfma_f32_16x16x32_bf16(afA0, bf0, accA, 0, 0, 0);
            accA = __builtin_amdgcn_mfma_f32_16x16x32_bf16(afA1, bf1, accA, 0, 0, 0);
            accB = __builtin_amdgcn_mfma_f32_16x16x32_bf16(afB0, bf0, accB, 0, 0, 0);
            accB = __builtin_amdgcn_mfma_f32_16x16x32_bf16(afB1, bf1, accB, 0, 0, 0);
            __hip_bfloat16* dst = (p == 0) ? h : res;
            if (full) {
                #pragma unroll
                for (int r = 0; r < 4; ++r)
                    dst[(size_t)(rowbaseA + r) * 256 + coll] = __float2bfloat16(accA[r]);
                #pragma unroll
                for (int r = 0; r < 4; ++r)
                    dst[(size_t)(rowbaseB + r) * 256 + coll] = __float2bfloat16(accB[r]);
            } else {
                #pragma unroll
                for (int r = 0; r < 4; ++r) {
                    int rn = rowbaseA + r;
                    if (rn < N_NODES) dst[(size_t)rn * 256 + coll] = __float2bfloat16(accA[r]);
                }
                #pragma unroll
                for (int r = 0; r < 4; ++r) {
                    int rn = rowbaseB + r;
                    if (rn < N_NODES) dst[(size_t)rn * 256 + coll] = __float2bfloat16(accB[r]);
                }
            }
        }
        if (p == 1) {
            // ---- logit tile: cols 0..3 = a_src heads, 4..7 = a_dst heads ----
            int coll = lane & 15;
            bf16x8 bf0 = *(bf16x8*)&As[coll * 64 + (kg ^ amask)];
            bf16x8 bf1 = *(bf16x8*)&As[coll * 64 + ((32 + kg) ^ amask)];
            f32x4 accA = {0.f, 0.f, 0.f, 0.f};
            f32x4 accB = {0.f, 0.f, 0.f, 0.f};
            accA = __builtin_amdgcn_mfma_f32_16x16x32_bf16(afA0, bf0, accA, 0, 0, 0);
            accA = __builtin_amdgcn_mfma_f32_16x16x32_bf16(afA1, bf1, accA, 0, 0, 0);
            accB = __builtin_amdgcn_mfma_f32_16x16x32_bf16(afB0, bf0, accB, 0, 0, 0);
            accB = __builtin_amdgcn_mfma_f32_16x16x32_bf16(afB1, bf1, accB, 0, 0, 0);
            #pragma unroll
            for (int r = 0; r < 4; ++r) {
                int rn = rowbaseA + r;
                if (rn < N_NODES) {
                    if (coll < 4)      a_src[rn * 4 + coll] = accA[r];
                    else if (coll < 8) a_dst[rn * 4 + (coll - 4)] = accA[r];
                }
            }
            #pragma unroll
            for (int r = 0; r < 4; ++r) {
                int rn = rowbaseB + r;
                if (rn < N_NODES) {
                    if (coll < 4)      a_src[rn * 4 + coll] = accB[r];
                    else if (coll < 8) a_dst[rn * 4 + (coll - 4)] = accB[r];
                }
            }
        }
    }
}

// ---- FUSED: softmax (raw-e table, deferred 1/z) + gather x8 + bf16 res + elu + mix + update ----
__global__ __launch_bounds__(256) void fused_gat_kernel(
        const int* __restrict__ rp, const int* __restrict__ col,
        const float* __restrict__ a_src, const float* __restrict__ a_dst,
        const __hip_bfloat16* __restrict__ h,
        const float* __restrict__ conv_b,
        const __hip_bfloat16* __restrict__ res,
        float* __restrict__ Y, float* __restrict__ X) {
    __shared__ float satt[4][64][4];   // per-wave RAW exp weights (unnormalized)
    __shared__ int   scol[4][64];      // per-wave src byte-offsets (s*512)
    int n = (blockIdx.x * blockDim.x + threadIdx.x) >> 6;
    if (n >= N_NODES) return;
    int lane = threadIdx.x & 63;
    int w = (threadIdx.x >> 6) & 3;
    int head = lane >> 4;
    int base = rp[n];
    int deg  = rp[n + 1] - base;
    const char* hb = (const char*)h;
    size_t loff = (size_t)lane * 8;
    float4 ad = ((const float4*)a_dst)[n];

    float a0 = 0.f, a1 = 0.f, a2 = 0.f, a3 = 0.f;
    float invz;

    if (deg <= 64) {
        int s = 0;
        float l0 = -3.0e38f, l1 = -3.0e38f, l2 = -3.0e38f, l3 = -3.0e38f;
        if (lane < deg) {
            s = col[base + lane];                       // coalesced
            float4 as = ((const float4*)a_src)[s];      // one 16B gather per edge
            l0 = lrelu(as.x + ad.x); l1 = lrelu(as.y + ad.y);
            l2 = lrelu(as.z + ad.z); l3 = lrelu(as.w + ad.w);
        }
        float m0 = l0, m1 = l1, m2 = l2, m3 = l3;
        #pragma unroll
        for (int off = 1; off < 64; off <<= 1) {
            m0 = fmaxf(m0, __shfl_xor(m0, off)); m1 = fmaxf(m1, __shfl_xor(m1, off));
            m2 = fmaxf(m2, __shfl_xor(m2, off)); m3 = fmaxf(m3, __shfl_xor(m3, off));
        }
        float e0 = (lane < deg) ? __expf(l0 - m0) : 0.f;
        float e1 = (lane < deg) ? __expf(l1 - m1) : 0.f;
        float e2 = (lane < deg) ? __expf(l2 - m2) : 0.f;
        float e3 = (lane < deg) ? __expf(l3 - m3) : 0.f;
        float z0 = e0, z1 = e1, z2 = e2, z3 = e3;
        #pragma unroll
        for (int off = 1; off < 64; off <<= 1) {
            z0 += __shfl_xor(z0, off); z1 += __shfl_xor(z1, off);
            z2 += __shfl_xor(z2, off); z3 += __shfl_xor(z3, off);
        }
        // raw-e table (wave-synchronous); normalization deferred to epilogue
        satt[w][lane][0] = e0; satt[w][lane][1] = e1;
        satt[w][lane][2] = e2; satt[w][lane][3] = e3;
        scol[w][lane] = s << 9;          // byte offset: s * 256 ushorts * 2B
        float zh = (head == 0) ? z0 : (head == 1) ? z1 : (head == 2) ? z2 : z3;
        invz = 1.0f / zh;

        int j = 0;
        for (; j + 8 <= deg; j += 8) {       // 8 gathers in flight
            int   s0 = scol[w][j],       s1 = scol[w][j + 1];
            int   s2 = scol[w][j + 2],   s3 = scol[w][j + 3];
            int   s4 = scol[w][j + 4],   s5 = scol[w][j + 5];
            int   s6 = scol[w][j + 6],   s7 = scol[w][j + 7];
            float w0 = satt[w][j][head],     w1 = satt[w][j + 1][head];
            float w2 = satt[w][j + 2][head], w3 = satt[w][j + 3][head];
            float w4 = satt[w][j + 4][head], w5 = satt[w][j + 5][head];
            float w6 = satt[w][j + 6][head], w7 = satt[w][j + 7][head];
            ushort4 v0 = *(const ushort4*)(hb + s0 + loff);
            ushort4 v1 = *(const ushort4*)(hb + s1 + loff);
            ushort4 v2 = *(const ushort4*)(hb + s2 + loff);
            ushort4 v3 = *(const ushort4*)(hb + s3 + loff);
            ushort4 v4 = *(const ushort4*)(hb + s4 + loff);
            ushort4 v5 = *(const ushort4*)(hb + s5 + loff);
            ushort4 v6 = *(const ushort4*)(hb + s6 + loff);
            ushort4 v7 = *(const ushort4*)(hb + s7 + loff);
            a0 += w0 * bf2f(v0.x) + w1 * bf2f(v1.x) + w2 * bf2f(v2.x) + w3 * bf2f(v3.x)
                + w4 * bf2f(v4.x) + w5 * bf2f(v5.x) + w6 * bf2f(v6.x) + w7 * bf2f(v7.x);
            a1 += w0 * bf2f(v0.y) + w1 * bf2f(v1.y) + w2 * bf2f(v2.y) + w3 * bf2f(v3.y)
                + w4 * bf2f(v4.y) + w5 * bf2f(v5.y) + w6 * bf2f(v6.y) + w7 * bf2f(v7.y);
            a2 += w0 * bf2f(v0.z) + w1 * bf2f(v1.z) + w2 * bf2f(v2.z) + w3 * bf2f(v3.z)
                + w4 * bf2f(v4.z) + w5 * bf2f(v5.z) + w6 * bf2f(v6.z) + w7 * bf2f(v7.z);
            a3 += w0 * bf2f(v0.w) + w1 * bf2f(v1.w) + w2 * bf2f(v2.w) + w3 * bf2f(v3.w)
                + w4 * bf2f(v4.w) + w5 * bf2f(v5.w) + w6 * bf2f(v6.w) + w7 * bf2f(v7.w);
        }
        for (; j + 4 <= deg; j += 4) {
            int   s0 = scol[w][j],       s1 = scol[w][j + 1];
            int   s2 = scol[w][j + 2],   s3 = scol[w][j + 3];
            float w0 = satt[w][j][head],     w1 = satt[w][j + 1][head];
            float w2 = satt[w][j + 2][head], w3 = satt[w][j + 3][head];
            ushort4 v0 = *(const ushort4*)(hb + s0 + loff);
            ushort4 v1 = *(const ushort4*)(hb + s1 + loff);
            ushort4 v2 = *(const ushort4*)(hb + s2 + loff);
            ushort4 v3 = *(const ushort4*)(hb + s3 + loff);
            a0 += w0 * bf2f(v0.x) + w1 * bf2f(v1.x) + w2 * bf2f(v2.x) + w3 * bf2f(v3.x);
            a1 += w0 * bf2f(v0.y) + w1 * bf2f(v1.y) + w2 * bf2f(v2.y) + w3 * bf2f(v3.y);
            a2 += w0 * bf2f(v0.z) + w1 * bf2f(v1.z) + w2 * bf2f(v2.z) + w3 * bf2f(v3.z);
            a3 += w0 * bf2f(v0.w) + w1 * bf2f(v1.w) + w2 * bf2f(v2.w) + w3 * bf2f(v3.w);
        }
        for (; j < deg; ++j) {
            int   s0 = scol[w][j];
            float w0 = satt[w][j][head];
            ushort4 v0 = *(const ushort4*)(hb + s0 + loff);
            a0 += w0 * bf2f(v0.x); a1 += w0 * bf2f(v0.y);
            a2 += w0 * bf2f(v0.z); a3 += w0 * bf2f(v0.w);
        }
    } else {
        // ---- rare fallback (deg > 64): chunked online softmax, then weighted gather ----
        float m0 = -3.0e38f, m1 = -3.0e38f, m2 = -3.0e38f, m3 = -3.0e38f;
        float z0 = 0.f, z1 = 0.f, z2 = 0.f, z3 = 0.f;
        for (int c0 = 0; c0 < deg; c0 += 64) {
            int j = c0 + lane;
            float l0 = -3.0e38f, l1 = -3.0e38f, l2 = -3.0e38f, l3 = -3.0e38f;
            if (j < deg) {
                int s = col[base + j];
                float4 as = ((const float4*)a_src)[s];
                l0 = lrelu(as.x + ad.x); l1 = lrelu(as.y + ad.y);
                l2 = lrelu(as.z + ad.z); l3 = lrelu(as.w + ad.w);
            }
            float c0m = l0, c1m = l1, c2m = l2, c3m = l3;
            #pragma unroll
            for (int off = 1; off < 64; off <<= 1) {
                c0m = fmaxf(c0m, __shfl_xor(c0m, off)); c1m = fmaxf(c1m, __shfl_xor(c1m, off));
                c2m = fmaxf(c2m, __shfl_xor(c2m, off)); c3m = fmaxf(c3m, __shfl_xor(c3m, off));
            }
            float n0 = fmaxf(m0, c0m), n1 = fmaxf(m1, c1m);
            float n2 = fmaxf(m2, c2m), n3 = fmaxf(m3, c3m);
            z0 *= __expf(m0 - n0); z1 *= __expf(m1 - n1);
            z2 *= __expf(m2 - n2); z3 *= __expf(m3 - n3);
            m0 = n0; m1 = n1; m2 = n2; m3 = n3;
            float e0 = (j < deg) ? __expf(l0 - m0) : 0.f;
            float e1 = (j < deg) ? __expf(l1 - m1) : 0.f;
            float e2 = (j < deg) ? __expf(l2 - m2) : 0.f;
            float e3 = (j < deg) ? __expf(l3 - m3) : 0.f;
            #pragma unroll
            for (int off = 1; off < 64; off <<= 1) {
                e0 += __shfl_xor(e0, off); e1 += __shfl_xor(e1, off);
                e2 += __shfl_xor(e2, off); e3 += __shfl_xor(e3, off);
            }
            z0 += e0; z1 += e1; z2 += e2; z3 += e3;
        }
        float zh = (head == 0) ? z0 : (head == 1) ? z1 : (head == 2) ? z2 : z3;
        invz = 1.0f / zh;
        for (int c0 = 0; c0 < deg; c0 += 64) {
            int j = c0 + lane;
            int s = 0;
            float e0 = 0.f, e1 = 0.f, e2 = 0.f, e3 = 0.f;
            if (j < deg) {
                s = col[base + j];
                float4 as = ((const float4*)a_src)[s];
                e0 = __expf(lrelu(as.x + ad.x) - m0);
                e1 = __expf(lrelu(as.y + ad.y) - m1);
                e2 = __expf(lrelu(as.z + ad.z) - m2);
                e3 = __expf(lrelu(as.w + ad.w) - m3);
            }
            satt[w][lane][0] = e0; satt[w][lane][1] = e1;
            satt[w][lane][2] = e2; satt[w][lane][3] = e3;
            scol[w][lane] = s << 9;
            int cnt = min(64, deg - c0);
            for (int jj = 0; jj < cnt; ++jj) {
                int   sj = scol[w][jj];
                float ww = satt[w][jj][head];
                ushort4 v = *(const ushort4*)(hb + sj + loff);
                a0 += ww * bf2f(v.x); a1 += ww * bf2f(v.y);
                a2 += ww * bf2f(v.z); a3 += ww * bf2f(v.w);
            }
        }
    }

    // ---- deferred normalization, bf16 residual, elu, lane-local head-mix, update ----
    a0 *= invz; a1 *= invz; a2 *= invz; a3 *= invz;
    ushort4 rr4 = ((const ushort4*)res)[(size_t)n * 64 + lane];   // 8B/lane coalesced
    float4 cb = ((const float4*)conv_b)[lane];
    float v0 = a0 + cb.x + bf2f(rr4.x), v1 = a1 + cb.y + bf2f(rr4.y);
    float v2 = a2 + cb.z + bf2f(rr4.z), v3 = a3 + cb.w + bf2f(rr4.w);
    v0 = (v0 > 0.f) ? v0 : (__expf(v0) - 1.f);
    v1 = (v1 > 0.f) ? v1 : (__expf(v1) - 1.f);
    v2 = (v2 > 0.f) ? v2 : (__expf(v2) - 1.f);
    v3 = (v3 > 0.f) ? v3 : (__expf(v3) - 1.f);
    float mixed = 0.25f * (v0 + v1 + v2 + v3);

    float xv = X[n * 64 + lane];
    float y = Y[n * 64 + lane];
    y  = y + (mixed - y - xv);    // DT=ALPHA=GAMMA=1
    xv = xv + y;
    Y[n * 64 + lane] = y;
    X[n * 64 + lane] = xv;
}

// ---------------- decoder: per-block partials (no global atomics) ----------------
__global__ void decoder_partial_kernel(const float* __restrict__ X, const float* __restrict__ dec_w,
                                       const float* __restrict__ dec_b, const int* __restrict__ batch,
                                       float* __restrict__ partials) {
    __shared__ float sg[N_GRAPHS];
    int t = threadIdx.x;                      // 256 threads = 4 waves
    if (t < N_GRAPHS) sg[t] = 0.f;
    __syncthreads();
    int lane = t & 63;
    int wave = t >> 6;
    const int npb = (N_NODES + DEC_BLOCKS - 1) / DEC_BLOCKS;   // 98
    int start = blockIdx.x * npb;
    int end   = min(start + npb, N_NODES);
    float dw = dec_w[lane];
    float db = dec_b[0];
    for (int n = start + wave; n < end; n += 4) {
        float p = X[n * 64 + lane] * dw;
        #pragma unroll
        for (int off = 32; off >= 1; off >>= 1) p += __shfl_down(p, off);
        if (lane == 0) atomicAdd(&sg[batch[n]], p + db);
    }
    __syncthreads();
    if (t < N_GRAPHS) partials[blockIdx.x * N_GRAPHS + t] = sg[t];
}

__global__ void decoder_reduce_kernel(const float* __restrict__ partials, float* __restrict__ out) {
    __shared__ float red[256];
    int t = threadIdx.x;
    int g = t & 63, j = t >> 6;
    float s = 0.f;
    for (int b = j * (DEC_BLOCKS / 4); b < (j + 1) * (DEC_BLOCKS / 4); ++b)
        s += partials[b * N_GRAPHS + g];
    red[t] = s;
    __syncthreads();
    if (t < 64) out[g] = red[g] + red[64 + g] + red[128 + g] + red[192 + g];
}

extern "C" void kernel_launch(void* const* d_in, const int* in_sizes, int n_in,
                              void* d_out, int out_size, void* d_ws, size_t ws_size,
                              hipStream_t stream) {
    const float* x       = (const float*)d_in[0];
    const float* pos     = (const float*)d_in[1];
    const int*   ei      = (const int*)d_in[2];
    const int*   batch   = (const int*)d_in[3];
    const float* enc_w   = (const float*)d_in[4];
    const float* enc_b   = (const float*)d_in[5];
    const float* res_w   = (const float*)d_in[6];
    const float* res_b   = (const float*)d_in[7];
    const float* lin_w   = (const float*)d_in[8];
    const float* att_src = (const float*)d_in[9];
    const float* att_dst = (const float*)d_in[10];
    const float* conv_b  = (const float*)d_in[11];
    const float* dec_w   = (const float*)d_in[12];
    const float* dec_b   = (const float*)d_in[13];
    float* out = (float*)d_out;

    char* ws = (char*)d_ws;
    size_t off = 0;
    auto alloc = [&](size_t bytes) -> void* {
        void* p = ws + off;
        off += (bytes + 255) & ~size_t(255);
        return p;
    };
    float* Y       = (float*)alloc((size_t)N_NODES * 64 * sizeof(float));
    float* X       = (float*)alloc((size_t)N_NODES * 64 * sizeof(float));
    __hip_bfloat16* h   = (__hip_bfloat16*)alloc((size_t)N_NODES * HW * sizeof(__hip_bfloat16));
    __hip_bfloat16* res = (__hip_bfloat16*)alloc((size_t)N_NODES * HW * sizeof(__hip_bfloat16));
    float* a_src   = (float*)alloc((size_t)N_NODES * NHEADS * sizeof(float));
    float* a_dst   = (float*)alloc((size_t)N_NODES * NHEADS * sizeof(float));
    unsigned short* Wt = (unsigned short*)alloc((size_t)528 * 64 * sizeof(unsigned short));
    float* partials= (float*)alloc((size_t)DEC_BLOCKS * N_GRAPHS * sizeof(float));
    int*   counts  = (int*)alloc((size_t)N_NODES * sizeof(int));
    int*   row_ptr = (int*)alloc((size_t)(N_NODES + 1) * sizeof(int));
    int*   cursor  = (int*)alloc((size_t)N_NODES * sizeof(int));
    int*   col     = (int*)alloc((size_t)E_TOT * sizeof(int));
    int*   bsum    = (int*)alloc((size_t)SCAN_NB * sizeof(int));
    int*   boff    = (int*)alloc((size_t)SCAN_NB * sizeof(int));

    // ---- CSR build (dst is static; built each call for determinism) ----
    hipMemsetAsync(counts, 0, (size_t)N_NODES * sizeof(int), stream);
    const int eb = (E_TOT + 255) / 256;
    hist_kernel<<<eb, 256, 0, stream>>>(ei, counts);
    scan_reduce_kernel<<<SCAN_NB, 256, 0, stream>>>(counts, bsum);
    scan_bsum_kernel<<<1, 256, 0, stream>>>(bsum, boff);
    scan_write_kernel<<<SCAN_NB, 256, 0, stream>>>(counts, boff, row_ptr, cursor);
    scatter_kernel<<<eb, 256, 0, stream>>>(ei, cursor, col);

    prep_wt_kernel<<<64, 256, 0, stream>>>(lin_w, res_w, att_src, att_dst, Wt);
    encoder_kernel<<<(N_NODES + ENC_NPB - 1) / ENC_NPB, 256, 0, stream>>>(
        x, pos, enc_w, enc_b, Y, X);

    const int ab = (N_NODES * 64 + 255) / 256;   // one wave per node
    const int mb = (N_NODES + MFMA_NPB - 1) / MFMA_NPB;   // 391
    for (int layer = 0; layer < 3; ++layer) {
        lin_mfma_kernel<<<mb, 256, 0, stream>>>(X, Wt, h, res, a_src, a_dst);
        fused_gat_kernel<<<ab, 256, 0, stream>>>(row_ptr, col, a_src, a_dst, h,
                                                 conv_b, res, Y, X);
    }

    decoder_partial_kernel<<<DEC_BLOCKS, 256, 0, stream>>>(X, dec_w, dec_b, batch, partials);
    decoder_reduce_kernel<<<1, 256, 0, stream>>>(partials, out);
}